// Round 4
// baseline (839.591 us; speedup 1.0000x reference)
//
#include <hip/hip_runtime.h>

#define NN 50000
#define EE 400000

// workspace offsets (in floats)
#define WS_SUMS 0
#define WS_CNT  (NN*64)          // 3,200,000
#define WS_XW1  3250000          // N*128 floats

__device__ __forceinline__ void fma4(float4& a, float s, const float4& w){
  a.x = fmaf(s, w.x, a.x);
  a.y = fmaf(s, w.y, a.y);
  a.z = fmaf(s, w.z, a.z);
  a.w = fmaf(s, w.w, a.w);
}

__device__ __forceinline__ unsigned rotl32(unsigned v, int d){ return (v<<d)|(v>>(32-d)); }

// jax.random.normal(key(42), (50000,32), f32) under jax_threefry_partitionable=True:
// counter (0, idx), bits = x0 ^ x1, uniform -> sqrt(2)*ErfInv32. Verified R3.
__device__ __forceinline__ float eps_at(unsigned idx){
  const unsigned k0 = 0u, k1 = 42u, k2 = 0x1BD11BDAu ^ 0u ^ 42u;
  unsigned x0 = 0u + k0, x1 = idx + k1;   // counter (0, idx)
  const int rotA[4] = {13,15,26,6};
  const int rotB[4] = {17,29,16,24};
  #pragma unroll
  for (int i=0;i<4;i++){ x0 += x1; x1 = rotl32(x1, rotA[i]); x1 ^= x0; }
  x0 += k1; x1 += k2 + 1u;
  #pragma unroll
  for (int i=0;i<4;i++){ x0 += x1; x1 = rotl32(x1, rotB[i]); x1 ^= x0; }
  x0 += k2; x1 += k0 + 2u;
  #pragma unroll
  for (int i=0;i<4;i++){ x0 += x1; x1 = rotl32(x1, rotA[i]); x1 ^= x0; }
  x0 += k0; x1 += k1 + 3u;
  #pragma unroll
  for (int i=0;i<4;i++){ x0 += x1; x1 = rotl32(x1, rotB[i]); x1 ^= x0; }
  x0 += k1; x1 += k2 + 4u;
  #pragma unroll
  for (int i=0;i<4;i++){ x0 += x1; x1 = rotl32(x1, rotA[i]); x1 ^= x0; }
  x0 += k2; x1 += k0 + 5u;
  unsigned bits = x0 ^ x1;   // partitionable 32-bit fold
  float f = __uint_as_float((bits >> 9) | 0x3f800000u) - 1.0f;  // [0,1)
  const float lo = -0.99999994f;
  float u = f * 2.0f + lo;
  u = fmaxf(u, lo);
  float w = -log1pf(-u*u);
  float p;
  if (w < 5.0f){
    w -= 2.5f;
    p = 2.81022636e-08f;
    p = fmaf(p,w, 3.43273939e-07f);
    p = fmaf(p,w,-3.5233877e-06f);
    p = fmaf(p,w,-4.39150654e-06f);
    p = fmaf(p,w, 0.00021858087f);
    p = fmaf(p,w,-0.00125372503f);
    p = fmaf(p,w,-0.00417768164f);
    p = fmaf(p,w, 0.246640727f);
    p = fmaf(p,w, 1.50140941f);
  } else {
    w = sqrtf(w) - 3.0f;
    p = -0.000200214257f;
    p = fmaf(p,w, 0.000100950558f);
    p = fmaf(p,w, 0.00134934322f);
    p = fmaf(p,w,-0.00367342844f);
    p = fmaf(p,w, 0.00573950773f);
    p = fmaf(p,w,-0.0076224613f);
    p = fmaf(p,w, 0.00943887047f);
    p = fmaf(p,w, 1.00167406f);
    p = fmaf(p,w, 2.83297682f);
  }
  return 1.41421356237f * (p * u);
}

// ---------------- kernel 1: xW1 = x @ W1[0:64,:]  [N,128] ----------------
// No LDS: A-rows read via all-lanes-same-address broadcast (L1-served).
__global__ __launch_bounds__(256) void k_xw1(const float* __restrict__ x,
                                             const float* __restrict__ W1,
                                             float* __restrict__ xW1){
  const int tid = threadIdx.x;
  const int base = blockIdx.x * 64;
  const int jq = tid & 31;     // 32 quads -> 128 cols
  const int rb = tid >> 5;     // 8 groups of 8 rows
  float4 acc[8];
  #pragma unroll
  for (int r=0;r<8;r++) acc[r] = make_float4(0.f,0.f,0.f,0.f);
  int rown[8];
  #pragma unroll
  for (int r=0;r<8;r++){ int n = base + rb*8 + r; rown[r] = (n < NN) ? n : (NN-1); }
  for (int k=0;k<64;k+=4){
    float4 w0 = *(const float4*)(W1 + (k+0)*128 + 4*jq);
    float4 w1 = *(const float4*)(W1 + (k+1)*128 + 4*jq);
    float4 w2 = *(const float4*)(W1 + (k+2)*128 + 4*jq);
    float4 w3 = *(const float4*)(W1 + (k+3)*128 + 4*jq);
    #pragma unroll
    for (int r=0;r<8;r++){
      float4 z = *(const float4*)(x + rown[r]*64 + k);   // broadcast within half-wave
      fma4(acc[r], z.x, w0); fma4(acc[r], z.y, w1);
      fma4(acc[r], z.z, w2); fma4(acc[r], z.w, w3);
    }
  }
  #pragma unroll
  for (int r=0;r<8;r++){
    int n = base + rb*8 + r;
    if (n < NN) *(float4*)(xW1 + n*128 + 4*jq) = acc[r];
  }
}

// ---------------- kernel 2: edge MLP + scatter (1 barrier) ----------------
#define H1STR 132   // padded stride (128+4): GEMM2 row-spacing 528%32=16 -> 2-way (free)
__global__ __launch_bounds__(256, 4) void k_edge(const int* __restrict__ ei,
    const float* __restrict__ ea, const float* __restrict__ xW1,
    const float* __restrict__ W1, const float* __restrict__ b1,
    const float* __restrict__ g1, const float* __restrict__ be1,
    const float* __restrict__ W2, const float* __restrict__ b2,
    float* __restrict__ sums, float* __restrict__ cnt){
  __shared__ __align__(16) float h1[64*H1STR];   // 33,792 B -> 4 blocks/CU
  const int tid = threadIdx.x;
  const int base = blockIdx.x * 64;
  // ---- GEMM1 + in-register LN + ReLU ----
  {
    const int jq = tid & 31, rb = tid >> 5;   // half-wave owns 8 rows x (4 cols each lane)
    float4 acc[8];
    #pragma unroll
    for (int r=0;r<8;r++){
      int row = ei[base + rb*8 + r];          // L1 broadcast
      acc[r] = *(const float4*)(xW1 + (size_t)row*128 + 4*jq);  // gather (coalesced 512B/row)
    }
    const float* eab = ea + (size_t)(base + rb*8)*64;
    for (int k=0;k<64;k+=4){
      float4 w0 = *(const float4*)(W1 + (64+k+0)*128 + 4*jq);
      float4 w1 = *(const float4*)(W1 + (64+k+1)*128 + 4*jq);
      float4 w2 = *(const float4*)(W1 + (64+k+2)*128 + 4*jq);
      float4 w3 = *(const float4*)(W1 + (64+k+3)*128 + 4*jq);
      #pragma unroll
      for (int r=0;r<8;r++){
        float4 z = *(const float4*)(eab + r*64 + k);   // same addr across 32 lanes -> broadcast
        fma4(acc[r], z.x, w0); fma4(acc[r], z.y, w1);
        fma4(acc[r], z.z, w2); fma4(acc[r], z.w, w3);
      }
    }
    float4 bb  = *(const float4*)(b1 + 4*jq);
    float4 gg  = *(const float4*)(g1 + 4*jq);
    float4 bet = *(const float4*)(be1 + 4*jq);
    #pragma unroll
    for (int r=0;r<8;r++){
      float4 v = acc[r];
      v.x += bb.x; v.y += bb.y; v.z += bb.z; v.w += bb.w;
      float s  = v.x + v.y + v.z + v.w;
      float ss = fmaf(v.x,v.x, fmaf(v.y,v.y, fmaf(v.z,v.z, v.w*v.w)));
      #pragma unroll
      for (int off=16; off; off>>=1){ s += __shfl_xor(s,off); ss += __shfl_xor(ss,off); }
      float mean = s * (1.0f/128.0f);
      float inv  = rsqrtf(ss*(1.0f/128.0f) - mean*mean + 1e-5f);
      float4 o;
      o.x = fmaxf(fmaf((v.x-mean)*inv, gg.x, bet.x), 0.f);
      o.y = fmaxf(fmaf((v.y-mean)*inv, gg.y, bet.y), 0.f);
      o.z = fmaxf(fmaf((v.z-mean)*inv, gg.z, bet.z), 0.f);
      o.w = fmaxf(fmaf((v.w-mean)*inv, gg.w, bet.w), 0.f);
      *(float4*)(h1 + (rb*8+r)*H1STR + 4*jq) = o;
    }
  }
  __syncthreads();
  // ---- GEMM2 + atomic scatter ----
  {
    const int jq = tid & 15, rb = tid >> 4;   // 16 groups x 4 rows
    int mycols[4];
    #pragma unroll
    for (int r=0;r<4;r++) mycols[r] = ei[EE + base + rb*4 + r];
    float4 acc[4];
    #pragma unroll
    for (int r=0;r<4;r++) acc[r] = make_float4(0.f,0.f,0.f,0.f);
    for (int k=0;k<128;k+=4){
      float4 w0 = *(const float4*)(W2 + (k+0)*64 + 4*jq);
      float4 w1 = *(const float4*)(W2 + (k+1)*64 + 4*jq);
      float4 w2 = *(const float4*)(W2 + (k+2)*64 + 4*jq);
      float4 w3 = *(const float4*)(W2 + (k+3)*64 + 4*jq);
      #pragma unroll
      for (int r=0;r<4;r++){
        float4 z = *(const float4*)(h1 + (rb*4+r)*H1STR + k);
        fma4(acc[r], z.x, w0); fma4(acc[r], z.y, w1);
        fma4(acc[r], z.z, w2); fma4(acc[r], z.w, w3);
      }
    }
    float4 bb = *(const float4*)(b2 + 4*jq);
    #pragma unroll
    for (int r=0;r<4;r++){
      float* dst = sums + (size_t)mycols[r]*64 + 4*jq;
      atomicAdd(dst+0, acc[r].x + bb.x);
      atomicAdd(dst+1, acc[r].y + bb.y);
      atomicAdd(dst+2, acc[r].z + bb.z);
      atomicAdd(dst+3, acc[r].w + bb.w);
    }
  }
  if (tid < 64) atomicAdd(cnt + ei[EE + base + tid], 1.0f);
}

// ---------------- kernel 3: node MLP + heads + reparam (5 barriers) ----------------
#define T2STR 132
#define ZSSTR 36
__global__ __launch_bounds__(256, 3) void k_node(const float* __restrict__ x,
    const float* __restrict__ u, const int* __restrict__ batch,
    const float* __restrict__ sums, const float* __restrict__ cnt,
    const float* __restrict__ W3, const float* __restrict__ b3,
    const float* __restrict__ g3, const float* __restrict__ be3,
    const float* __restrict__ W4, const float* __restrict__ b4,
    const float* __restrict__ g4, const float* __restrict__ be4,
    const float* __restrict__ Wm, const float* __restrict__ bm,
    const float* __restrict__ Wv, const float* __restrict__ bv,
    const float* __restrict__ Wx, const float* __restrict__ bx,
    float* __restrict__ out){
  __shared__ __align__(16) float zS[32*160];   // z (160) -> t2 (132) -> zs (36)
  __shared__ __align__(16) float h3S[32*256];  // h3 -> hm (32x64 mu|lv)
  const int tid = threadIdx.x;
  const int base = blockIdx.x * 32;
  // build z = [x | sums/deg | u[batch]]  (32 x 160), inline cnt/batch gathers
  #pragma unroll
  for (int i=0;i<5;i++){
    int f0 = (tid + 256*i)*4;
    int r = f0 / 160;
    int c = f0 - r*160;
    int n = base + r;
    float4 v = make_float4(0.f,0.f,0.f,0.f);
    if (n < NN){
      if (c < 64) v = *(const float4*)(x + n*64 + c);
      else if (c < 128){
        v = *(const float4*)(sums + n*64 + (c-64));
        float rc = 1.0f / fmaxf(cnt[n], 1.0f);
        v.x *= rc; v.y *= rc; v.z *= rc; v.w *= rc;
      } else {
        v = *(const float4*)(u + batch[n]*32 + (c-128));
      }
    }
    *(float4*)(zS + f0) = v;
  }
  __syncthreads();   // B0
  // GEMM1: h3 = relu(LN(z @ W3 + b3)) — LN in-register, full-wave
  {
    const int jq = tid & 63, rb = tid >> 6;   // wave rb owns rows rb*8..+7
    float4 acc[8];
    #pragma unroll
    for (int r=0;r<8;r++) acc[r] = make_float4(0.f,0.f,0.f,0.f);
    for (int k=0;k<160;k+=4){
      float4 w0 = *(const float4*)(W3 + (k+0)*256 + 4*jq);
      float4 w1 = *(const float4*)(W3 + (k+1)*256 + 4*jq);
      float4 w2 = *(const float4*)(W3 + (k+2)*256 + 4*jq);
      float4 w3v= *(const float4*)(W3 + (k+3)*256 + 4*jq);
      #pragma unroll
      for (int r=0;r<8;r++){
        float4 z = *(const float4*)(zS + (rb*8+r)*160 + k);   // wave-uniform addr -> LDS broadcast
        fma4(acc[r], z.x, w0); fma4(acc[r], z.y, w1);
        fma4(acc[r], z.z, w2); fma4(acc[r], z.w, w3v);
      }
    }
    float4 bb  = *(const float4*)(b3 + 4*jq);
    float4 gg  = *(const float4*)(g3 + 4*jq);
    float4 bet = *(const float4*)(be3 + 4*jq);
    #pragma unroll
    for (int r=0;r<8;r++){
      float4 v = acc[r];
      v.x += bb.x; v.y += bb.y; v.z += bb.z; v.w += bb.w;
      float s  = v.x + v.y + v.z + v.w;
      float ss = fmaf(v.x,v.x, fmaf(v.y,v.y, fmaf(v.z,v.z, v.w*v.w)));
      #pragma unroll
      for (int off=32; off; off>>=1){ s += __shfl_xor(s,off); ss += __shfl_xor(ss,off); }
      float mean = s * (1.0f/256.0f);
      float inv  = rsqrtf(ss*(1.0f/256.0f) - mean*mean + 1e-5f);
      float4 o;
      o.x = fmaxf(fmaf((v.x-mean)*inv, gg.x, bet.x), 0.f);
      o.y = fmaxf(fmaf((v.y-mean)*inv, gg.y, bet.y), 0.f);
      o.z = fmaxf(fmaf((v.z-mean)*inv, gg.z, bet.z), 0.f);
      o.w = fmaxf(fmaf((v.w-mean)*inv, gg.w, bet.w), 0.f);
      *(float4*)(h3S + (rb*8+r)*256 + 4*jq) = o;
    }
  }
  __syncthreads();   // B1
  // GEMM2: t2 = relu(LN(h3 @ W4 + b4)) — LN in-register, half-wave; t2 overlays zS
  {
    const int jq = tid & 31, rb = tid >> 5;   // 8 groups x 4 rows
    float4 acc[4];
    #pragma unroll
    for (int r=0;r<4;r++) acc[r] = make_float4(0.f,0.f,0.f,0.f);
    for (int k=0;k<256;k+=4){
      float4 w0 = *(const float4*)(W4 + (k+0)*128 + 4*jq);
      float4 w1 = *(const float4*)(W4 + (k+1)*128 + 4*jq);
      float4 w2 = *(const float4*)(W4 + (k+2)*128 + 4*jq);
      float4 w3 = *(const float4*)(W4 + (k+3)*128 + 4*jq);
      #pragma unroll
      for (int r=0;r<4;r++){
        float4 z = *(const float4*)(h3S + (rb*4+r)*256 + k);
        fma4(acc[r], z.x, w0); fma4(acc[r], z.y, w1);
        fma4(acc[r], z.z, w2); fma4(acc[r], z.w, w3);
      }
    }
    float4 bb  = *(const float4*)(b4 + 4*jq);
    float4 gg  = *(const float4*)(g4 + 4*jq);
    float4 bet = *(const float4*)(be4 + 4*jq);
    #pragma unroll
    for (int r=0;r<4;r++){
      float4 v = acc[r];
      v.x += bb.x; v.y += bb.y; v.z += bb.z; v.w += bb.w;
      float s  = v.x + v.y + v.z + v.w;
      float ss = fmaf(v.x,v.x, fmaf(v.y,v.y, fmaf(v.z,v.z, v.w*v.w)));
      #pragma unroll
      for (int off=16; off; off>>=1){ s += __shfl_xor(s,off); ss += __shfl_xor(ss,off); }
      float mean = s * (1.0f/128.0f);
      float inv  = rsqrtf(ss*(1.0f/128.0f) - mean*mean + 1e-5f);
      float4 o;
      o.x = fmaxf(fmaf((v.x-mean)*inv, gg.x, bet.x), 0.f);
      o.y = fmaxf(fmaf((v.y-mean)*inv, gg.y, bet.y), 0.f);
      o.z = fmaxf(fmaf((v.z-mean)*inv, gg.z, bet.z), 0.f);
      o.w = fmaxf(fmaf((v.w-mean)*inv, gg.w, bet.w), 0.f);
      *(float4*)(zS + (rb*4+r)*T2STR + 4*jq) = o;   // overlays z (dead since B1)
    }
  }
  __syncthreads();   // B2
  // heads: hm = t2 @ [Wm|Wv] + [bm|bv]; store mu/lv to out; hm overlays h3S
  {
    const int jq = tid & 15, rb = tid >> 4;   // 16 groups x 2 rows
    const float* Wp = (jq < 8) ? Wm : Wv;
    const int cq = (jq & 7) * 4;
    float4 acc[2];
    #pragma unroll
    for (int r=0;r<2;r++) acc[r] = make_float4(0.f,0.f,0.f,0.f);
    for (int k=0;k<128;k+=4){
      float4 w0 = *(const float4*)(Wp + (k+0)*32 + cq);
      float4 w1 = *(const float4*)(Wp + (k+1)*32 + cq);
      float4 w2 = *(const float4*)(Wp + (k+2)*32 + cq);
      float4 w3 = *(const float4*)(Wp + (k+3)*32 + cq);
      #pragma unroll
      for (int r=0;r<2;r++){
        float4 z = *(const float4*)(zS + (rb*2+r)*T2STR + k);
        fma4(acc[r], z.x, w0); fma4(acc[r], z.y, w1);
        fma4(acc[r], z.z, w2); fma4(acc[r], z.w, w3);
      }
    }
    const float* bp = (jq < 8) ? bm : bv;
    float4 bb = *(const float4*)(bp + cq);
    const long long sec = (jq < 8) ? (long long)NN*64 : ((long long)NN*64 + (long long)NN*32);
    #pragma unroll
    for (int r=0;r<2;r++){
      float4 v = acc[r];
      v.x += bb.x; v.y += bb.y; v.z += bb.z; v.w += bb.w;
      int rr = rb*2 + r;
      *(float4*)(h3S + rr*64 + ((jq<8)?0:32) + cq) = v;
      int n = base + rr;
      if (n < NN) *(float4*)(out + sec + (long long)n*32 + cq) = v;
    }
  }
  __syncthreads();   // B3
  // reparameterize: zs = mu + eps * exp(0.5*lv)  (zs overlays zS, stride 36)
  #pragma unroll
  for (int i=0;i<4;i++){
    int l = tid + 256*i;
    int r = l >> 5, jj = l & 31;
    float mu = h3S[r*64 + jj];
    float lv = h3S[r*64 + 32 + jj];
    unsigned idx = (unsigned)((base + r)*32 + jj);
    float e = eps_at(idx);
    zS[r*ZSSTR + jj] = fmaf(e, expf(0.5f*lv), mu);
  }
  __syncthreads();   // B4
  // out[32][64] = zs @ Wx + bx
  {
    const int jq = tid & 15, rb = tid >> 4;
    float4 acc[2];
    #pragma unroll
    for (int r=0;r<2;r++) acc[r] = make_float4(0.f,0.f,0.f,0.f);
    for (int k=0;k<32;k+=4){
      float4 w0 = *(const float4*)(Wx + (k+0)*64 + 4*jq);
      float4 w1 = *(const float4*)(Wx + (k+1)*64 + 4*jq);
      float4 w2 = *(const float4*)(Wx + (k+2)*64 + 4*jq);
      float4 w3 = *(const float4*)(Wx + (k+3)*64 + 4*jq);
      #pragma unroll
      for (int r=0;r<2;r++){
        float4 z = *(const float4*)(zS + (rb*2+r)*ZSSTR + k);
        fma4(acc[r], z.x, w0); fma4(acc[r], z.y, w1);
        fma4(acc[r], z.z, w2); fma4(acc[r], z.w, w3);
      }
    }
    float4 bb = *(const float4*)(bx + 4*jq);
    #pragma unroll
    for (int r=0;r<2;r++){
      int n = base + rb*2 + r;
      if (n < NN){
        float4 v = acc[r];
        v.x += bb.x; v.y += bb.y; v.z += bb.z; v.w += bb.w;
        *(float4*)(out + (long long)n*64 + 4*jq) = v;
      }
    }
  }
}

extern "C" void kernel_launch(void* const* d_in, const int* in_sizes, int n_in,
                              void* d_out, int out_size, void* d_ws, size_t ws_size,
                              hipStream_t stream) {
  const float* x     = (const float*)d_in[0];
  const int*   ei    = (const int*)d_in[1];     // int32
  const float* ea    = (const float*)d_in[2];
  const float* u     = (const float*)d_in[3];
  const int*   batch = (const int*)d_in[4];     // int32
  // d_in[5] = goal (unused)
  const float* W1 = (const float*)d_in[6];
  const float* b1 = (const float*)d_in[7];
  const float* g1 = (const float*)d_in[8];
  const float* be1= (const float*)d_in[9];
  const float* W2 = (const float*)d_in[10];
  const float* b2 = (const float*)d_in[11];
  const float* W3 = (const float*)d_in[12];
  const float* b3 = (const float*)d_in[13];
  const float* g3 = (const float*)d_in[14];
  const float* be3= (const float*)d_in[15];
  const float* W4 = (const float*)d_in[16];
  const float* b4 = (const float*)d_in[17];
  const float* g4 = (const float*)d_in[18];
  const float* be4= (const float*)d_in[19];
  const float* Wm = (const float*)d_in[20];
  const float* bm = (const float*)d_in[21];
  const float* Wv = (const float*)d_in[22];
  const float* bv = (const float*)d_in[23];
  const float* Wx = (const float*)d_in[24];
  const float* bx = (const float*)d_in[25];

  float* ws   = (float*)d_ws;
  float* sums = ws + WS_SUMS;
  float* cnt  = ws + WS_CNT;
  float* xW1  = ws + WS_XW1;
  float* out  = (float*)d_out;

  hipMemsetAsync(sums, 0, (size_t)(NN*64 + NN)*sizeof(float), stream);

  k_xw1 <<<(NN+63)/64, 256, 0, stream>>>(x, W1, xW1);
  k_edge<<<EE/64,      256, 0, stream>>>(ei, ea, xW1, W1, b1, g1, be1, W2, b2, sums, cnt);
  k_node<<<(NN+31)/32, 256, 0, stream>>>(x, u, batch, sums, cnt,
                                         W3,b3,g3,be3, W4,b4,g4,be4,
                                         Wm,bm, Wv,bv, Wx,bx, out);
}

// Round 5
// 742.449 us; speedup vs baseline: 1.1308x; 1.1308x over previous
//
#include <hip/hip_runtime.h>

#define NN 50000
#define EE 400000
#define NB 49   // ceil(NN/1024) scan blocks

__device__ __forceinline__ void fma4(float4& a, float s, const float4& w){
  a.x = fmaf(s, w.x, a.x);
  a.y = fmaf(s, w.y, a.y);
  a.z = fmaf(s, w.z, a.z);
  a.w = fmaf(s, w.w, a.w);
}

__device__ __forceinline__ unsigned rotl32(unsigned v, int d){ return (v<<d)|(v>>(32-d)); }

// jax.random.normal(key(42), (50000,32), f32) under jax_threefry_partitionable=True:
// counter (0, idx), bits = x0 ^ x1, uniform -> sqrt(2)*ErfInv32. Verified R3.
__device__ __forceinline__ float eps_at(unsigned idx){
  const unsigned k0 = 0u, k1 = 42u, k2 = 0x1BD11BDAu ^ 0u ^ 42u;
  unsigned x0 = 0u + k0, x1 = idx + k1;   // counter (0, idx)
  const int rotA[4] = {13,15,26,6};
  const int rotB[4] = {17,29,16,24};
  #pragma unroll
  for (int i=0;i<4;i++){ x0 += x1; x1 = rotl32(x1, rotA[i]); x1 ^= x0; }
  x0 += k1; x1 += k2 + 1u;
  #pragma unroll
  for (int i=0;i<4;i++){ x0 += x1; x1 = rotl32(x1, rotB[i]); x1 ^= x0; }
  x0 += k2; x1 += k0 + 2u;
  #pragma unroll
  for (int i=0;i<4;i++){ x0 += x1; x1 = rotl32(x1, rotA[i]); x1 ^= x0; }
  x0 += k0; x1 += k1 + 3u;
  #pragma unroll
  for (int i=0;i<4;i++){ x0 += x1; x1 = rotl32(x1, rotB[i]); x1 ^= x0; }
  x0 += k1; x1 += k2 + 4u;
  #pragma unroll
  for (int i=0;i<4;i++){ x0 += x1; x1 = rotl32(x1, rotA[i]); x1 ^= x0; }
  x0 += k2; x1 += k0 + 5u;
  unsigned bits = x0 ^ x1;   // partitionable 32-bit fold
  float f = __uint_as_float((bits >> 9) | 0x3f800000u) - 1.0f;  // [0,1)
  const float lo = -0.99999994f;
  float u = f * 2.0f + lo;
  u = fmaxf(u, lo);
  float w = -log1pf(-u*u);
  float p;
  if (w < 5.0f){
    w -= 2.5f;
    p = 2.81022636e-08f;
    p = fmaf(p,w, 3.43273939e-07f);
    p = fmaf(p,w,-3.5233877e-06f);
    p = fmaf(p,w,-4.39150654e-06f);
    p = fmaf(p,w, 0.00021858087f);
    p = fmaf(p,w,-0.00125372503f);
    p = fmaf(p,w,-0.00417768164f);
    p = fmaf(p,w, 0.246640727f);
    p = fmaf(p,w, 1.50140941f);
  } else {
    w = sqrtf(w) - 3.0f;
    p = -0.000200214257f;
    p = fmaf(p,w, 0.000100950558f);
    p = fmaf(p,w, 0.00134934322f);
    p = fmaf(p,w,-0.00367342844f);
    p = fmaf(p,w, 0.00573950773f);
    p = fmaf(p,w,-0.0076224613f);
    p = fmaf(p,w, 0.00943887047f);
    p = fmaf(p,w, 1.00167406f);
    p = fmaf(p,w, 2.83297682f);
  }
  return 1.41421356237f * (p * u);
}

// ================= CSR construction =================
__global__ __launch_bounds__(256) void k_hist(const int* __restrict__ ei, int* __restrict__ cnt){
  int e = blockIdx.x*256 + threadIdx.x;
  if (e < EE) atomicAdd(&cnt[ei[EE + e]], 1);
}

// exclusive scan, step 1: per-block (1024 elems) scan + block totals
__global__ __launch_bounds__(256) void k_scan1(const int* __restrict__ cnt,
                                               int* __restrict__ offs,
                                               int* __restrict__ partials){
  __shared__ int sdata[256];
  const int t = threadIdx.x, b = blockIdx.x;
  const int base = b*1024 + t*4;
  int v0 = (base+0 < NN) ? cnt[base+0] : 0;
  int v1 = (base+1 < NN) ? cnt[base+1] : 0;
  int v2 = (base+2 < NN) ? cnt[base+2] : 0;
  int v3 = (base+3 < NN) ? cnt[base+3] : 0;
  int tsum = v0+v1+v2+v3;
  sdata[t] = tsum;
  __syncthreads();
  for (int off=1; off<256; off<<=1){
    int add = (t >= off) ? sdata[t-off] : 0;
    __syncthreads();
    sdata[t] += add;
    __syncthreads();
  }
  int run = sdata[t] - tsum;   // exclusive prefix for this thread
  if (base+0 < NN) offs[base+0] = run;  run += v0;
  if (base+1 < NN) offs[base+1] = run;  run += v1;
  if (base+2 < NN) offs[base+2] = run;  run += v2;
  if (base+3 < NN) offs[base+3] = run;
  if (t == 255) partials[b] = sdata[255];
}

// step 2: exclusive scan of the NB block totals (single wave)
__global__ __launch_bounds__(64) void k_scan2(int* __restrict__ partials){
  int l = threadIdx.x;
  int v = (l < NB) ? partials[l] : 0;
  int inc = v;
  #pragma unroll
  for (int off=1; off<64; off<<=1){
    int t = __shfl_up(inc, off);
    if (l >= off) inc += t;
  }
  if (l < NB) partials[l] = inc - v;   // exclusive
}

// step 3: add block offsets; also init cursor = offs
__global__ __launch_bounds__(256) void k_scan3(int* __restrict__ offs,
                                               const int* __restrict__ partials,
                                               int* __restrict__ cursor){
  const int t = threadIdx.x, b = blockIdx.x;
  const int base = b*1024 + t*4;
  int add = partials[b];
  #pragma unroll
  for (int k=0;k<4;k++){
    int i = base + k;
    if (i < NN){ int o = offs[i] + add; offs[i] = o; cursor[i] = o; }
  }
}

__global__ __launch_bounds__(256) void k_fill(const int* __restrict__ ei,
                                              int* __restrict__ cursor,
                                              int* __restrict__ eidx){
  int e = blockIdx.x*256 + threadIdx.x;
  if (e < EE){
    int c = ei[EE + e];
    int pos = atomicAdd(&cursor[c], 1);
    eidx[pos] = e;
  }
}

// ---------------- kernel 1: xW1 = x @ W1[0:64,:]  [N,128] ----------------
__global__ __launch_bounds__(256) void k_xw1(const float* __restrict__ x,
                                             const float* __restrict__ W1,
                                             float* __restrict__ xW1){
  const int tid = threadIdx.x;
  const int base = blockIdx.x * 64;
  const int jq = tid & 31;     // 32 quads -> 128 cols
  const int rb = tid >> 5;     // 8 groups of 8 rows
  float4 acc[8];
  #pragma unroll
  for (int r=0;r<8;r++) acc[r] = make_float4(0.f,0.f,0.f,0.f);
  int rown[8];
  #pragma unroll
  for (int r=0;r<8;r++){ int n = base + rb*8 + r; rown[r] = (n < NN) ? n : (NN-1); }
  for (int k=0;k<64;k+=4){
    float4 w0 = *(const float4*)(W1 + (k+0)*128 + 4*jq);
    float4 w1 = *(const float4*)(W1 + (k+1)*128 + 4*jq);
    float4 w2 = *(const float4*)(W1 + (k+2)*128 + 4*jq);
    float4 w3 = *(const float4*)(W1 + (k+3)*128 + 4*jq);
    #pragma unroll
    for (int r=0;r<8;r++){
      float4 z = *(const float4*)(x + rown[r]*64 + k);   // broadcast within half-wave
      fma4(acc[r], z.x, w0); fma4(acc[r], z.y, w1);
      fma4(acc[r], z.z, w2); fma4(acc[r], z.w, w3);
    }
  }
  #pragma unroll
  for (int r=0;r<8;r++){
    int n = base + rb*8 + r;
    if (n < NN) *(float4*)(xW1 + n*128 + 4*jq) = acc[r];
  }
}

// ---------------- kernel 2: edge MLP -> h_ws (NO atomics) ----------------
#define H1STR 132
__global__ __launch_bounds__(256, 4) void k_edge(const int* __restrict__ ei,
    const float* __restrict__ ea, const float* __restrict__ xW1,
    const float* __restrict__ W1, const float* __restrict__ b1,
    const float* __restrict__ g1, const float* __restrict__ be1,
    const float* __restrict__ W2, const float* __restrict__ b2,
    float* __restrict__ h_ws){
  __shared__ __align__(16) float h1[64*H1STR];   // 33,792 B -> 4 blocks/CU
  const int tid = threadIdx.x;
  const int base = blockIdx.x * 64;
  // ---- GEMM1 + in-register LN + ReLU ----
  {
    const int jq = tid & 31, rb = tid >> 5;
    float4 acc[8];
    #pragma unroll
    for (int r=0;r<8;r++){
      int row = ei[base + rb*8 + r];
      acc[r] = *(const float4*)(xW1 + (size_t)row*128 + 4*jq);
    }
    const float* eab = ea + (size_t)(base + rb*8)*64;
    for (int k=0;k<64;k+=4){
      float4 w0 = *(const float4*)(W1 + (64+k+0)*128 + 4*jq);
      float4 w1 = *(const float4*)(W1 + (64+k+1)*128 + 4*jq);
      float4 w2 = *(const float4*)(W1 + (64+k+2)*128 + 4*jq);
      float4 w3 = *(const float4*)(W1 + (64+k+3)*128 + 4*jq);
      #pragma unroll
      for (int r=0;r<8;r++){
        float4 z = *(const float4*)(eab + r*64 + k);
        fma4(acc[r], z.x, w0); fma4(acc[r], z.y, w1);
        fma4(acc[r], z.z, w2); fma4(acc[r], z.w, w3);
      }
    }
    float4 bb  = *(const float4*)(b1 + 4*jq);
    float4 gg  = *(const float4*)(g1 + 4*jq);
    float4 bet = *(const float4*)(be1 + 4*jq);
    #pragma unroll
    for (int r=0;r<8;r++){
      float4 v = acc[r];
      v.x += bb.x; v.y += bb.y; v.z += bb.z; v.w += bb.w;
      float s  = v.x + v.y + v.z + v.w;
      float ss = fmaf(v.x,v.x, fmaf(v.y,v.y, fmaf(v.z,v.z, v.w*v.w)));
      #pragma unroll
      for (int off=16; off; off>>=1){ s += __shfl_xor(s,off); ss += __shfl_xor(ss,off); }
      float mean = s * (1.0f/128.0f);
      float inv  = rsqrtf(ss*(1.0f/128.0f) - mean*mean + 1e-5f);
      float4 o;
      o.x = fmaxf(fmaf((v.x-mean)*inv, gg.x, bet.x), 0.f);
      o.y = fmaxf(fmaf((v.y-mean)*inv, gg.y, bet.y), 0.f);
      o.z = fmaxf(fmaf((v.z-mean)*inv, gg.z, bet.z), 0.f);
      o.w = fmaxf(fmaf((v.w-mean)*inv, gg.w, bet.w), 0.f);
      *(float4*)(h1 + (rb*8+r)*H1STR + 4*jq) = o;
    }
  }
  __syncthreads();
  // ---- GEMM2 -> plain stores to h_ws ----
  {
    const int jq = tid & 15, rb = tid >> 4;   // 16 groups x 4 rows
    float4 acc[4];
    #pragma unroll
    for (int r=0;r<4;r++) acc[r] = make_float4(0.f,0.f,0.f,0.f);
    for (int k=0;k<128;k+=4){
      float4 w0 = *(const float4*)(W2 + (k+0)*64 + 4*jq);
      float4 w1 = *(const float4*)(W2 + (k+1)*64 + 4*jq);
      float4 w2 = *(const float4*)(W2 + (k+2)*64 + 4*jq);
      float4 w3 = *(const float4*)(W2 + (k+3)*64 + 4*jq);
      #pragma unroll
      for (int r=0;r<4;r++){
        float4 z = *(const float4*)(h1 + (rb*4+r)*H1STR + k);
        fma4(acc[r], z.x, w0); fma4(acc[r], z.y, w1);
        fma4(acc[r], z.z, w2); fma4(acc[r], z.w, w3);
      }
    }
    float4 bb = *(const float4*)(b2 + 4*jq);
    #pragma unroll
    for (int r=0;r<4;r++){
      float4 v = acc[r];
      v.x += bb.x; v.y += bb.y; v.z += bb.z; v.w += bb.w;
      *(float4*)(h_ws + (size_t)(base + rb*4 + r)*64 + 4*jq) = v;
    }
  }
}

// ---------------- kernel 3: CSR-aggregate + node MLP + heads + reparam ----------------
#define T2STR 132
#define ZSSTR 36
__global__ __launch_bounds__(256, 3) void k_node(const float* __restrict__ x,
    const float* __restrict__ u, const int* __restrict__ batch,
    const float* __restrict__ h_ws, const int* __restrict__ cnt,
    const int* __restrict__ offs, const int* __restrict__ eidx,
    const float* __restrict__ W3, const float* __restrict__ b3,
    const float* __restrict__ g3, const float* __restrict__ be3,
    const float* __restrict__ W4, const float* __restrict__ b4,
    const float* __restrict__ g4, const float* __restrict__ be4,
    const float* __restrict__ Wm, const float* __restrict__ bm,
    const float* __restrict__ Wv, const float* __restrict__ bv,
    const float* __restrict__ Wx, const float* __restrict__ bx,
    float* __restrict__ out){
  __shared__ __align__(16) float zS[32*160];   // z (160) -> t2 (132) -> zs (36)
  __shared__ __align__(16) float h3S[32*256];  // h3 -> hm (32x64 mu|lv)
  const int tid = threadIdx.x;
  const int base = blockIdx.x * 32;
  // ---- build z = [x | csr-mean(h) | u[batch]] ----
  #pragma unroll
  for (int i=0;i<2;i++){           // x: 16 float4 per row
    int l = tid + 256*i;
    int r = l >> 4, c4 = (l & 15) * 4;
    int n = base + r;
    float4 v = make_float4(0.f,0.f,0.f,0.f);
    if (n < NN) v = *(const float4*)(x + (size_t)n*64 + c4);
    *(float4*)(zS + r*160 + c4) = v;
  }
  {                                 // u[batch]: 8 float4 per row
    int r = tid >> 3, c4 = (tid & 7) * 4;
    int n = base + r;
    float4 v = make_float4(0.f,0.f,0.f,0.f);
    if (n < NN) v = *(const float4*)(u + (size_t)batch[n]*32 + c4);
    *(float4*)(zS + r*160 + 128 + c4) = v;
  }
  {                                 // aggs: 8 threads per node, 8 floats each
    int r = tid >> 3, p = tid & 7;
    int n = base + r;
    float4 a0 = make_float4(0.f,0.f,0.f,0.f), a1 = a0;
    int deg = 0;
    if (n < NN){
      deg = cnt[n];
      int start = offs[n];
      for (int j=0;j<deg;j++){
        int e = eidx[start + j];
        const float* hp = h_ws + (size_t)e*64 + p*8;
        float4 v0 = *(const float4*)(hp);
        float4 v1 = *(const float4*)(hp + 4);
        a0.x += v0.x; a0.y += v0.y; a0.z += v0.z; a0.w += v0.w;
        a1.x += v1.x; a1.y += v1.y; a1.z += v1.z; a1.w += v1.w;
      }
    }
    float rc = 1.0f / fmaxf((float)deg, 1.0f);
    a0.x*=rc; a0.y*=rc; a0.z*=rc; a0.w*=rc;
    a1.x*=rc; a1.y*=rc; a1.z*=rc; a1.w*=rc;
    *(float4*)(zS + r*160 + 64 + p*8)     = a0;
    *(float4*)(zS + r*160 + 64 + p*8 + 4) = a1;
  }
  __syncthreads();   // B0
  // GEMM1: h3 = relu(LN(z @ W3 + b3)) — LN in-register, full-wave
  {
    const int jq = tid & 63, rb = tid >> 6;
    float4 acc[8];
    #pragma unroll
    for (int r=0;r<8;r++) acc[r] = make_float4(0.f,0.f,0.f,0.f);
    for (int k=0;k<160;k+=4){
      float4 w0 = *(const float4*)(W3 + (k+0)*256 + 4*jq);
      float4 w1 = *(const float4*)(W3 + (k+1)*256 + 4*jq);
      float4 w2 = *(const float4*)(W3 + (k+2)*256 + 4*jq);
      float4 w3v= *(const float4*)(W3 + (k+3)*256 + 4*jq);
      #pragma unroll
      for (int r=0;r<8;r++){
        float4 z = *(const float4*)(zS + (rb*8+r)*160 + k);
        fma4(acc[r], z.x, w0); fma4(acc[r], z.y, w1);
        fma4(acc[r], z.z, w2); fma4(acc[r], z.w, w3v);
      }
    }
    float4 bb  = *(const float4*)(b3 + 4*jq);
    float4 gg  = *(const float4*)(g3 + 4*jq);
    float4 bet = *(const float4*)(be3 + 4*jq);
    #pragma unroll
    for (int r=0;r<8;r++){
      float4 v = acc[r];
      v.x += bb.x; v.y += bb.y; v.z += bb.z; v.w += bb.w;
      float s  = v.x + v.y + v.z + v.w;
      float ss = fmaf(v.x,v.x, fmaf(v.y,v.y, fmaf(v.z,v.z, v.w*v.w)));
      #pragma unroll
      for (int off=32; off; off>>=1){ s += __shfl_xor(s,off); ss += __shfl_xor(ss,off); }
      float mean = s * (1.0f/256.0f);
      float inv  = rsqrtf(ss*(1.0f/256.0f) - mean*mean + 1e-5f);
      float4 o;
      o.x = fmaxf(fmaf((v.x-mean)*inv, gg.x, bet.x), 0.f);
      o.y = fmaxf(fmaf((v.y-mean)*inv, gg.y, bet.y), 0.f);
      o.z = fmaxf(fmaf((v.z-mean)*inv, gg.z, bet.z), 0.f);
      o.w = fmaxf(fmaf((v.w-mean)*inv, gg.w, bet.w), 0.f);
      *(float4*)(h3S + (rb*8+r)*256 + 4*jq) = o;
    }
  }
  __syncthreads();   // B1
  // GEMM2: t2 = relu(LN(h3 @ W4 + b4)) — LN in-register, half-wave; t2 overlays zS
  {
    const int jq = tid & 31, rb = tid >> 5;
    float4 acc[4];
    #pragma unroll
    for (int r=0;r<4;r++) acc[r] = make_float4(0.f,0.f,0.f,0.f);
    for (int k=0;k<256;k+=4){
      float4 w0 = *(const float4*)(W4 + (k+0)*128 + 4*jq);
      float4 w1 = *(const float4*)(W4 + (k+1)*128 + 4*jq);
      float4 w2 = *(const float4*)(W4 + (k+2)*128 + 4*jq);
      float4 w3 = *(const float4*)(W4 + (k+3)*128 + 4*jq);
      #pragma unroll
      for (int r=0;r<4;r++){
        float4 z = *(const float4*)(h3S + (rb*4+r)*256 + k);
        fma4(acc[r], z.x, w0); fma4(acc[r], z.y, w1);
        fma4(acc[r], z.z, w2); fma4(acc[r], z.w, w3);
      }
    }
    float4 bb  = *(const float4*)(b4 + 4*jq);
    float4 gg  = *(const float4*)(g4 + 4*jq);
    float4 bet = *(const float4*)(be4 + 4*jq);
    #pragma unroll
    for (int r=0;r<4;r++){
      float4 v = acc[r];
      v.x += bb.x; v.y += bb.y; v.z += bb.z; v.w += bb.w;
      float s  = v.x + v.y + v.z + v.w;
      float ss = fmaf(v.x,v.x, fmaf(v.y,v.y, fmaf(v.z,v.z, v.w*v.w)));
      #pragma unroll
      for (int off=16; off; off>>=1){ s += __shfl_xor(s,off); ss += __shfl_xor(ss,off); }
      float mean = s * (1.0f/128.0f);
      float inv  = rsqrtf(ss*(1.0f/128.0f) - mean*mean + 1e-5f);
      float4 o;
      o.x = fmaxf(fmaf((v.x-mean)*inv, gg.x, bet.x), 0.f);
      o.y = fmaxf(fmaf((v.y-mean)*inv, gg.y, bet.y), 0.f);
      o.z = fmaxf(fmaf((v.z-mean)*inv, gg.z, bet.z), 0.f);
      o.w = fmaxf(fmaf((v.w-mean)*inv, gg.w, bet.w), 0.f);
      *(float4*)(zS + (rb*4+r)*T2STR + 4*jq) = o;
    }
  }
  __syncthreads();   // B2
  // heads: hm = t2 @ [Wm|Wv] + [bm|bv]; store mu/lv to out; hm overlays h3S
  {
    const int jq = tid & 15, rb = tid >> 4;
    const float* Wp = (jq < 8) ? Wm : Wv;
    const int cq = (jq & 7) * 4;
    float4 acc[2];
    #pragma unroll
    for (int r=0;r<2;r++) acc[r] = make_float4(0.f,0.f,0.f,0.f);
    for (int k=0;k<128;k+=4){
      float4 w0 = *(const float4*)(Wp + (k+0)*32 + cq);
      float4 w1 = *(const float4*)(Wp + (k+1)*32 + cq);
      float4 w2 = *(const float4*)(Wp + (k+2)*32 + cq);
      float4 w3 = *(const float4*)(Wp + (k+3)*32 + cq);
      #pragma unroll
      for (int r=0;r<2;r++){
        float4 z = *(const float4*)(zS + (rb*2+r)*T2STR + k);
        fma4(acc[r], z.x, w0); fma4(acc[r], z.y, w1);
        fma4(acc[r], z.z, w2); fma4(acc[r], z.w, w3);
      }
    }
    const float* bp = (jq < 8) ? bm : bv;
    float4 bb = *(const float4*)(bp + cq);
    const long long sec = (jq < 8) ? (long long)NN*64 : ((long long)NN*64 + (long long)NN*32);
    #pragma unroll
    for (int r=0;r<2;r++){
      float4 v = acc[r];
      v.x += bb.x; v.y += bb.y; v.z += bb.z; v.w += bb.w;
      int rr = rb*2 + r;
      *(float4*)(h3S + rr*64 + ((jq<8)?0:32) + cq) = v;
      int n = base + rr;
      if (n < NN) *(float4*)(out + sec + (long long)n*32 + cq) = v;
    }
  }
  __syncthreads();   // B3
  // reparameterize: zs = mu + eps * exp(0.5*lv)
  #pragma unroll
  for (int i=0;i<4;i++){
    int l = tid + 256*i;
    int r = l >> 5, jj = l & 31;
    float mu = h3S[r*64 + jj];
    float lv = h3S[r*64 + 32 + jj];
    unsigned idx = (unsigned)((base + r)*32 + jj);
    float e = eps_at(idx);
    zS[r*ZSSTR + jj] = fmaf(e, expf(0.5f*lv), mu);
  }
  __syncthreads();   // B4
  // out[32][64] = zs @ Wx + bx
  {
    const int jq = tid & 15, rb = tid >> 4;
    float4 acc[2];
    #pragma unroll
    for (int r=0;r<2;r++) acc[r] = make_float4(0.f,0.f,0.f,0.f);
    for (int k=0;k<32;k+=4){
      float4 w0 = *(const float4*)(Wx + (k+0)*64 + 4*jq);
      float4 w1 = *(const float4*)(Wx + (k+1)*64 + 4*jq);
      float4 w2 = *(const float4*)(Wx + (k+2)*64 + 4*jq);
      float4 w3 = *(const float4*)(Wx + (k+3)*64 + 4*jq);
      #pragma unroll
      for (int r=0;r<2;r++){
        float4 z = *(const float4*)(zS + (rb*2+r)*ZSSTR + k);
        fma4(acc[r], z.x, w0); fma4(acc[r], z.y, w1);
        fma4(acc[r], z.z, w2); fma4(acc[r], z.w, w3);
      }
    }
    float4 bb = *(const float4*)(bx + 4*jq);
    #pragma unroll
    for (int r=0;r<2;r++){
      int n = base + rb*2 + r;
      if (n < NN){
        float4 v = acc[r];
        v.x += bb.x; v.y += bb.y; v.z += bb.z; v.w += bb.w;
        *(float4*)(out + (long long)n*64 + 4*jq) = v;
      }
    }
  }
}

extern "C" void kernel_launch(void* const* d_in, const int* in_sizes, int n_in,
                              void* d_out, int out_size, void* d_ws, size_t ws_size,
                              hipStream_t stream) {
  const float* x     = (const float*)d_in[0];
  const int*   ei    = (const int*)d_in[1];     // int32
  const float* ea    = (const float*)d_in[2];
  const float* u     = (const float*)d_in[3];
  const int*   batch = (const int*)d_in[4];     // int32
  // d_in[5] = goal (unused)
  const float* W1 = (const float*)d_in[6];
  const float* b1 = (const float*)d_in[7];
  const float* g1 = (const float*)d_in[8];
  const float* be1= (const float*)d_in[9];
  const float* W2 = (const float*)d_in[10];
  const float* b2 = (const float*)d_in[11];
  const float* W3 = (const float*)d_in[12];
  const float* b3 = (const float*)d_in[13];
  const float* g3 = (const float*)d_in[14];
  const float* be3= (const float*)d_in[15];
  const float* W4 = (const float*)d_in[16];
  const float* b4 = (const float*)d_in[17];
  const float* g4 = (const float*)d_in[18];
  const float* be4= (const float*)d_in[19];
  const float* Wm = (const float*)d_in[20];
  const float* bm = (const float*)d_in[21];
  const float* Wv = (const float*)d_in[22];
  const float* bv = (const float*)d_in[23];
  const float* Wx = (const float*)d_in[24];
  const float* bx = (const float*)d_in[25];

  float* ws   = (float*)d_ws;
  float* xW1  = ws;                                    // N*128 f32 = 25.6 MB
  float* h_ws = ws + (size_t)NN*128;                   // E*64 f32 = 102.4 MB
  int*   cnt    = (int*)(ws + (size_t)NN*128 + (size_t)EE*64);
  int*   offs   = cnt + NN;
  int*   cursor = offs + NN;
  int*   eidx   = cursor + NN;                         // E ints
  int*   partials = eidx + EE;                         // NB ints
  float* out  = (float*)d_out;

  hipMemsetAsync(cnt, 0, (size_t)NN*sizeof(int), stream);

  k_hist <<<(EE+255)/256, 256, 0, stream>>>(ei, cnt);
  k_scan1<<<NB, 256, 0, stream>>>(cnt, offs, partials);
  k_scan2<<<1, 64, 0, stream>>>(partials);
  k_scan3<<<NB, 256, 0, stream>>>(offs, partials, cursor);
  k_fill <<<(EE+255)/256, 256, 0, stream>>>(ei, cursor, eidx);

  k_xw1 <<<(NN+63)/64, 256, 0, stream>>>(x, W1, xW1);
  k_edge<<<EE/64,      256, 0, stream>>>(ei, ea, xW1, W1, b1, g1, be1, W2, b2, h_ws);
  k_node<<<(NN+31)/32, 256, 0, stream>>>(x, u, batch, h_ws, cnt, offs, eidx,
                                         W3,b3,g3,be3, W4,b4,g4,be4,
                                         Wm,bm, Wv,bv, Wx,bx, out);
}

// Round 6
// 586.593 us; speedup vs baseline: 1.4313x; 1.2657x over previous
//
#include <hip/hip_runtime.h>

#define NN 50000
#define EE 400000
#define NB 49   // ceil(NN/1024) scan blocks

typedef __attribute__((ext_vector_type(8))) short bf16x8;
typedef __attribute__((ext_vector_type(4))) float f32x4;

__device__ __forceinline__ void fma4(float4& a, float s, const float4& w){
  a.x = fmaf(s, w.x, a.x);
  a.y = fmaf(s, w.y, a.y);
  a.z = fmaf(s, w.z, a.z);
  a.w = fmaf(s, w.w, a.w);
}

__device__ __forceinline__ unsigned short f2bf(float f){
  unsigned u = __float_as_uint(f);
  unsigned r = (u + 0x7fffu + ((u >> 16) & 1u)) >> 16;   // RNE
  return (unsigned short)r;
}

__device__ __forceinline__ bf16x8 cvt8(float4 lo, float4 hi){
  bf16x8 r;
  r[0]=(short)f2bf(lo.x); r[1]=(short)f2bf(lo.y); r[2]=(short)f2bf(lo.z); r[3]=(short)f2bf(lo.w);
  r[4]=(short)f2bf(hi.x); r[5]=(short)f2bf(hi.y); r[6]=(short)f2bf(hi.z); r[7]=(short)f2bf(hi.w);
  return r;
}

__device__ __forceinline__ unsigned rotl32(unsigned v, int d){ return (v<<d)|(v>>(32-d)); }

// jax.random.normal(key(42)) under jax_threefry_partitionable: counter (0,idx), bits=x0^x1. Verified R3.
__device__ __forceinline__ float eps_at(unsigned idx){
  const unsigned k0 = 0u, k1 = 42u, k2 = 0x1BD11BDAu ^ 0u ^ 42u;
  unsigned x0 = 0u + k0, x1 = idx + k1;
  const int rotA[4] = {13,15,26,6};
  const int rotB[4] = {17,29,16,24};
  #pragma unroll
  for (int i=0;i<4;i++){ x0 += x1; x1 = rotl32(x1, rotA[i]); x1 ^= x0; }
  x0 += k1; x1 += k2 + 1u;
  #pragma unroll
  for (int i=0;i<4;i++){ x0 += x1; x1 = rotl32(x1, rotB[i]); x1 ^= x0; }
  x0 += k2; x1 += k0 + 2u;
  #pragma unroll
  for (int i=0;i<4;i++){ x0 += x1; x1 = rotl32(x1, rotA[i]); x1 ^= x0; }
  x0 += k0; x1 += k1 + 3u;
  #pragma unroll
  for (int i=0;i<4;i++){ x0 += x1; x1 = rotl32(x1, rotB[i]); x1 ^= x0; }
  x0 += k1; x1 += k2 + 4u;
  #pragma unroll
  for (int i=0;i<4;i++){ x0 += x1; x1 = rotl32(x1, rotA[i]); x1 ^= x0; }
  x0 += k2; x1 += k0 + 5u;
  unsigned bits = x0 ^ x1;
  float f = __uint_as_float((bits >> 9) | 0x3f800000u) - 1.0f;
  const float lo = -0.99999994f;
  float u = f * 2.0f + lo;
  u = fmaxf(u, lo);
  float w = -log1pf(-u*u);
  float p;
  if (w < 5.0f){
    w -= 2.5f;
    p = 2.81022636e-08f;
    p = fmaf(p,w, 3.43273939e-07f);
    p = fmaf(p,w,-3.5233877e-06f);
    p = fmaf(p,w,-4.39150654e-06f);
    p = fmaf(p,w, 0.00021858087f);
    p = fmaf(p,w,-0.00125372503f);
    p = fmaf(p,w,-0.00417768164f);
    p = fmaf(p,w, 0.246640727f);
    p = fmaf(p,w, 1.50140941f);
  } else {
    w = sqrtf(w) - 3.0f;
    p = -0.000200214257f;
    p = fmaf(p,w, 0.000100950558f);
    p = fmaf(p,w, 0.00134934322f);
    p = fmaf(p,w,-0.00367342844f);
    p = fmaf(p,w, 0.00573950773f);
    p = fmaf(p,w,-0.0076224613f);
    p = fmaf(p,w, 0.00943887047f);
    p = fmaf(p,w, 1.00167406f);
    p = fmaf(p,w, 2.83297682f);
  }
  return 1.41421356237f * (p * u);
}

// ================= prep: bf16 conversions =================
__global__ __launch_bounds__(256) void k_prep_x(const float* __restrict__ x,
                                                unsigned short* __restrict__ xb){
  int t = blockIdx.x*256 + threadIdx.x;           // one bf16x8 per thread
  if (t < NN*64/8){
    const float4* p = (const float4*)(x + t*8);
    bf16x8 v = cvt8(p[0], p[1]);
    *(bf16x8*)(xb + t*8) = v;
  }
}

// W1T[n][k] = W1[k][n] (128x128), W2T[n][k] = W2[k][n] (64x128), bf16
__global__ __launch_bounds__(256) void k_prep_w(const float* __restrict__ W1,
                                                const float* __restrict__ W2,
                                                unsigned short* __restrict__ W1T,
                                                unsigned short* __restrict__ W2T){
  for (int i = threadIdx.x; i < 128*128; i += 256){
    int n = i >> 7, k = i & 127;
    W1T[i] = f2bf(W1[k*128 + n]);
  }
  for (int i = threadIdx.x; i < 64*128; i += 256){
    int n = i >> 7, k = i & 127;
    W2T[i] = f2bf(W2[k*64 + n]);
  }
}

// ================= CSR construction =================
__global__ __launch_bounds__(256) void k_hist(const int* __restrict__ ei, int* __restrict__ cnt){
  int e = blockIdx.x*256 + threadIdx.x;
  if (e < EE) atomicAdd(&cnt[ei[EE + e]], 1);
}

__global__ __launch_bounds__(256) void k_scan1(const int* __restrict__ cnt,
                                               int* __restrict__ offs,
                                               int* __restrict__ partials){
  __shared__ int sdata[256];
  const int t = threadIdx.x, b = blockIdx.x;
  const int base = b*1024 + t*4;
  int v0 = (base+0 < NN) ? cnt[base+0] : 0;
  int v1 = (base+1 < NN) ? cnt[base+1] : 0;
  int v2 = (base+2 < NN) ? cnt[base+2] : 0;
  int v3 = (base+3 < NN) ? cnt[base+3] : 0;
  int tsum = v0+v1+v2+v3;
  sdata[t] = tsum;
  __syncthreads();
  for (int off=1; off<256; off<<=1){
    int add = (t >= off) ? sdata[t-off] : 0;
    __syncthreads();
    sdata[t] += add;
    __syncthreads();
  }
  int run = sdata[t] - tsum;
  if (base+0 < NN) offs[base+0] = run;  run += v0;
  if (base+1 < NN) offs[base+1] = run;  run += v1;
  if (base+2 < NN) offs[base+2] = run;  run += v2;
  if (base+3 < NN) offs[base+3] = run;
  if (t == 255) partials[b] = sdata[255];
}

__global__ __launch_bounds__(64) void k_scan2(int* __restrict__ partials){
  int l = threadIdx.x;
  int v = (l < NB) ? partials[l] : 0;
  int inc = v;
  #pragma unroll
  for (int off=1; off<64; off<<=1){
    int t = __shfl_up(inc, off);
    if (l >= off) inc += t;
  }
  if (l < NB) partials[l] = inc - v;
}

__global__ __launch_bounds__(256) void k_scan3(int* __restrict__ offs,
                                               const int* __restrict__ partials,
                                               int* __restrict__ cursor){
  const int t = threadIdx.x, b = blockIdx.x;
  const int base = b*1024 + t*4;
  int add = partials[b];
  #pragma unroll
  for (int k=0;k<4;k++){
    int i = base + k;
    if (i < NN){ int o = offs[i] + add; offs[i] = o; cursor[i] = o; }
  }
}

__global__ __launch_bounds__(256) void k_fill(const int* __restrict__ ei,
                                              int* __restrict__ cursor,
                                              int* __restrict__ eidx){
  int e = blockIdx.x*256 + threadIdx.x;
  if (e < EE){
    int c = ei[EE + e];
    int pos = atomicAdd(&cursor[c], 1);
    eidx[pos] = e;
  }
}

// ---------------- kernel 2: edge MLP via MFMA -> h_ws ----------------
// GEMM1: M=64 edges, N=128, K=128 ([x_bf16[row] | cvt(ea)]);  LN+ReLU fp32 in LDS;
// GEMM2: M=64, N=64, K=128.  mfma_f32_16x16x32_bf16.
#define H1STR 132
__global__ __launch_bounds__(256, 4) void k_edge(const int* __restrict__ ei,
    const float* __restrict__ ea,
    const unsigned short* __restrict__ xb,
    const unsigned short* __restrict__ W1T, const float* __restrict__ b1,
    const float* __restrict__ g1, const float* __restrict__ be1,
    const unsigned short* __restrict__ W2T, const float* __restrict__ b2,
    float* __restrict__ h_ws){
  __shared__ __align__(16) float h1[64*H1STR];   // 33,792 B
  __shared__ int rows_l[64];
  const int tid  = threadIdx.x;
  const int base = blockIdx.x * 64;
  const int wv   = tid >> 6;        // wave 0..3
  const int lane = tid & 63;
  const int quad = lane >> 4;       // 0..3
  const int l16  = lane & 15;
  if (tid < 64) rows_l[tid] = ei[base + tid];
  __syncthreads();
  // ---- GEMM1: wave wv owns n-groups {2wv, 2wv+1}, all 4 m-groups ----
  {
    int rw[4];
    #pragma unroll
    for (int m=0;m<4;m++) rw[m] = rows_l[m*16 + l16];
    f32x4 acc[4][2];
    #pragma unroll
    for (int m=0;m<4;m++){ acc[m][0] = (f32x4){0.f,0.f,0.f,0.f}; acc[m][1] = (f32x4){0.f,0.f,0.f,0.f}; }
    #pragma unroll
    for (int ks=0; ks<4; ks++){
      bf16x8 af[4];
      if (ks < 2){
        #pragma unroll
        for (int m=0;m<4;m++)
          af[m] = *(const bf16x8*)(xb + (size_t)rw[m]*64 + ks*32 + quad*8);
      } else {
        #pragma unroll
        for (int m=0;m<4;m++){
          const float* p = ea + (size_t)(base + m*16 + l16)*64 + (ks-2)*32 + quad*8;
          af[m] = cvt8(*(const float4*)p, *(const float4*)(p+4));
        }
      }
      bf16x8 bf0 = *(const bf16x8*)(W1T + (size_t)((2*wv+0)*16 + l16)*128 + ks*32 + quad*8);
      bf16x8 bf1 = *(const bf16x8*)(W1T + (size_t)((2*wv+1)*16 + l16)*128 + ks*32 + quad*8);
      #pragma unroll
      for (int m=0;m<4;m++){
        acc[m][0] = __builtin_amdgcn_mfma_f32_16x16x32_bf16(af[m], bf0, acc[m][0], 0, 0, 0);
        acc[m][1] = __builtin_amdgcn_mfma_f32_16x16x32_bf16(af[m], bf1, acc[m][1], 0, 0, 0);
      }
    }
    // bias + scatter D (col=lane&15, row=quad*4+reg) into LDS fp32
    #pragma unroll
    for (int nl=0; nl<2; nl++){
      float b1c = b1[(2*wv+nl)*16 + l16];
      #pragma unroll
      for (int m=0;m<4;m++){
        #pragma unroll
        for (int r=0;r<4;r++)
          h1[(m*16 + quad*4 + r)*H1STR + (2*wv+nl)*16 + l16] = acc[m][nl][r] + b1c;
      }
    }
  }
  __syncthreads();
  // ---- LayerNorm(128) + ReLU (fp32, wave per row) ----
  {
    const float gA = g1[lane], gB = g1[lane+64];
    const float bA = be1[lane], bB = be1[lane+64];
    for (int r = wv*16; r < wv*16 + 16; ++r){
      float a = h1[r*H1STR + lane];
      float b = h1[r*H1STR + 64 + lane];
      float s = a + b, ss = fmaf(a,a,b*b);
      #pragma unroll
      for (int off=32; off; off>>=1){
        s  += __shfl_xor(s, off);
        ss += __shfl_xor(ss, off);
      }
      float mean = s * (1.0f/128.0f);
      float var  = ss * (1.0f/128.0f) - mean*mean;
      float inv = rsqrtf(var + 1e-5f);
      h1[r*H1STR + lane]      = fmaxf(fmaf((a-mean)*inv, gA, bA), 0.f);
      h1[r*H1STR + 64 + lane] = fmaxf(fmaf((b-mean)*inv, gB, bB), 0.f);
    }
  }
  __syncthreads();
  // ---- GEMM2: wave wv owns n-group wv, all 4 m-groups ----
  {
    f32x4 acc2[4];
    #pragma unroll
    for (int m=0;m<4;m++) acc2[m] = (f32x4){0.f,0.f,0.f,0.f};
    #pragma unroll
    for (int ks=0; ks<4; ks++){
      bf16x8 bfr = *(const bf16x8*)(W2T + (size_t)(wv*16 + l16)*128 + ks*32 + quad*8);
      #pragma unroll
      for (int m=0;m<4;m++){
        const float* p = h1 + (m*16 + l16)*H1STR + ks*32 + quad*8;
        bf16x8 af = cvt8(*(const float4*)p, *(const float4*)(p+4));
        acc2[m] = __builtin_amdgcn_mfma_f32_16x16x32_bf16(af, bfr, acc2[m], 0, 0, 0);
      }
    }
    float b2c = b2[wv*16 + l16];
    #pragma unroll
    for (int m=0;m<4;m++){
      #pragma unroll
      for (int r=0;r<4;r++)
        h_ws[(size_t)(base + m*16 + quad*4 + r)*64 + wv*16 + l16] = acc2[m][r] + b2c;
    }
  }
}

// ---------------- kernel 3: CSR-aggregate + node MLP + heads + reparam ----------------
#define T2STR 132
#define ZSSTR 36
__global__ __launch_bounds__(256, 3) void k_node(const float* __restrict__ x,
    const float* __restrict__ u, const int* __restrict__ batch,
    const float* __restrict__ h_ws, const int* __restrict__ cnt,
    const int* __restrict__ offs, const int* __restrict__ eidx,
    const float* __restrict__ W3, const float* __restrict__ b3,
    const float* __restrict__ g3, const float* __restrict__ be3,
    const float* __restrict__ W4, const float* __restrict__ b4,
    const float* __restrict__ g4, const float* __restrict__ be4,
    const float* __restrict__ Wm, const float* __restrict__ bm,
    const float* __restrict__ Wv, const float* __restrict__ bv,
    const float* __restrict__ Wx, const float* __restrict__ bx,
    float* __restrict__ out){
  __shared__ __align__(16) float zS[32*160];   // z (160) -> t2 (132) -> zs (36)
  __shared__ __align__(16) float h3S[32*256];  // h3 -> hm (32x64 mu|lv)
  const int tid = threadIdx.x;
  const int base = blockIdx.x * 32;
  #pragma unroll
  for (int i=0;i<2;i++){
    int l = tid + 256*i;
    int r = l >> 4, c4 = (l & 15) * 4;
    int n = base + r;
    float4 v = make_float4(0.f,0.f,0.f,0.f);
    if (n < NN) v = *(const float4*)(x + (size_t)n*64 + c4);
    *(float4*)(zS + r*160 + c4) = v;
  }
  {
    int r = tid >> 3, c4 = (tid & 7) * 4;
    int n = base + r;
    float4 v = make_float4(0.f,0.f,0.f,0.f);
    if (n < NN) v = *(const float4*)(u + (size_t)batch[n]*32 + c4);
    *(float4*)(zS + r*160 + 128 + c4) = v;
  }
  {
    int r = tid >> 3, p = tid & 7;
    int n = base + r;
    float4 a0 = make_float4(0.f,0.f,0.f,0.f), a1 = a0;
    int deg = 0;
    if (n < NN){
      deg = cnt[n];
      int start = offs[n];
      for (int j=0;j<deg;j++){
        int e = eidx[start + j];
        const float* hp = h_ws + (size_t)e*64 + p*8;
        float4 v0 = *(const float4*)(hp);
        float4 v1 = *(const float4*)(hp + 4);
        a0.x += v0.x; a0.y += v0.y; a0.z += v0.z; a0.w += v0.w;
        a1.x += v1.x; a1.y += v1.y; a1.z += v1.z; a1.w += v1.w;
      }
    }
    float rc = 1.0f / fmaxf((float)deg, 1.0f);
    a0.x*=rc; a0.y*=rc; a0.z*=rc; a0.w*=rc;
    a1.x*=rc; a1.y*=rc; a1.z*=rc; a1.w*=rc;
    *(float4*)(zS + r*160 + 64 + p*8)     = a0;
    *(float4*)(zS + r*160 + 64 + p*8 + 4) = a1;
  }
  __syncthreads();   // B0
  {
    const int jq = tid & 63, rb = tid >> 6;
    float4 acc[8];
    #pragma unroll
    for (int r=0;r<8;r++) acc[r] = make_float4(0.f,0.f,0.f,0.f);
    for (int k=0;k<160;k+=4){
      float4 w0 = *(const float4*)(W3 + (k+0)*256 + 4*jq);
      float4 w1 = *(const float4*)(W3 + (k+1)*256 + 4*jq);
      float4 w2 = *(const float4*)(W3 + (k+2)*256 + 4*jq);
      float4 w3v= *(const float4*)(W3 + (k+3)*256 + 4*jq);
      #pragma unroll
      for (int r=0;r<8;r++){
        float4 z = *(const float4*)(zS + (rb*8+r)*160 + k);
        fma4(acc[r], z.x, w0); fma4(acc[r], z.y, w1);
        fma4(acc[r], z.z, w2); fma4(acc[r], z.w, w3v);
      }
    }
    float4 bb  = *(const float4*)(b3 + 4*jq);
    float4 gg  = *(const float4*)(g3 + 4*jq);
    float4 bet = *(const float4*)(be3 + 4*jq);
    #pragma unroll
    for (int r=0;r<8;r++){
      float4 v = acc[r];
      v.x += bb.x; v.y += bb.y; v.z += bb.z; v.w += bb.w;
      float s  = v.x + v.y + v.z + v.w;
      float ss = fmaf(v.x,v.x, fmaf(v.y,v.y, fmaf(v.z,v.z, v.w*v.w)));
      #pragma unroll
      for (int off=32; off; off>>=1){ s += __shfl_xor(s,off); ss += __shfl_xor(ss,off); }
      float mean = s * (1.0f/256.0f);
      float inv  = rsqrtf(ss*(1.0f/256.0f) - mean*mean + 1e-5f);
      float4 o;
      o.x = fmaxf(fmaf((v.x-mean)*inv, gg.x, bet.x), 0.f);
      o.y = fmaxf(fmaf((v.y-mean)*inv, gg.y, bet.y), 0.f);
      o.z = fmaxf(fmaf((v.z-mean)*inv, gg.z, bet.z), 0.f);
      o.w = fmaxf(fmaf((v.w-mean)*inv, gg.w, bet.w), 0.f);
      *(float4*)(h3S + (rb*8+r)*256 + 4*jq) = o;
    }
  }
  __syncthreads();   // B1
  {
    const int jq = tid & 31, rb = tid >> 5;
    float4 acc[4];
    #pragma unroll
    for (int r=0;r<4;r++) acc[r] = make_float4(0.f,0.f,0.f,0.f);
    for (int k=0;k<256;k+=4){
      float4 w0 = *(const float4*)(W4 + (k+0)*128 + 4*jq);
      float4 w1 = *(const float4*)(W4 + (k+1)*128 + 4*jq);
      float4 w2 = *(const float4*)(W4 + (k+2)*128 + 4*jq);
      float4 w3 = *(const float4*)(W4 + (k+3)*128 + 4*jq);
      #pragma unroll
      for (int r=0;r<4;r++){
        float4 z = *(const float4*)(h3S + (rb*4+r)*256 + k);
        fma4(acc[r], z.x, w0); fma4(acc[r], z.y, w1);
        fma4(acc[r], z.z, w2); fma4(acc[r], z.w, w3);
      }
    }
    float4 bb  = *(const float4*)(b4 + 4*jq);
    float4 gg  = *(const float4*)(g4 + 4*jq);
    float4 bet = *(const float4*)(be4 + 4*jq);
    #pragma unroll
    for (int r=0;r<4;r++){
      float4 v = acc[r];
      v.x += bb.x; v.y += bb.y; v.z += bb.z; v.w += bb.w;
      float s  = v.x + v.y + v.z + v.w;
      float ss = fmaf(v.x,v.x, fmaf(v.y,v.y, fmaf(v.z,v.z, v.w*v.w)));
      #pragma unroll
      for (int off=16; off; off>>=1){ s += __shfl_xor(s,off); ss += __shfl_xor(ss,off); }
      float mean = s * (1.0f/128.0f);
      float inv  = rsqrtf(ss*(1.0f/128.0f) - mean*mean + 1e-5f);
      float4 o;
      o.x = fmaxf(fmaf((v.x-mean)*inv, gg.x, bet.x), 0.f);
      o.y = fmaxf(fmaf((v.y-mean)*inv, gg.y, bet.y), 0.f);
      o.z = fmaxf(fmaf((v.z-mean)*inv, gg.z, bet.z), 0.f);
      o.w = fmaxf(fmaf((v.w-mean)*inv, gg.w, bet.w), 0.f);
      *(float4*)(zS + (rb*4+r)*T2STR + 4*jq) = o;
    }
  }
  __syncthreads();   // B2
  {
    const int jq = tid & 15, rb = tid >> 4;
    const float* Wp = (jq < 8) ? Wm : Wv;
    const int cq = (jq & 7) * 4;
    float4 acc[2];
    #pragma unroll
    for (int r=0;r<2;r++) acc[r] = make_float4(0.f,0.f,0.f,0.f);
    for (int k=0;k<128;k+=4){
      float4 w0 = *(const float4*)(Wp + (k+0)*32 + cq);
      float4 w1 = *(const float4*)(Wp + (k+1)*32 + cq);
      float4 w2 = *(const float4*)(Wp + (k+2)*32 + cq);
      float4 w3 = *(const float4*)(Wp + (k+3)*32 + cq);
      #pragma unroll
      for (int r=0;r<2;r++){
        float4 z = *(const float4*)(zS + (rb*2+r)*T2STR + k);
        fma4(acc[r], z.x, w0); fma4(acc[r], z.y, w1);
        fma4(acc[r], z.z, w2); fma4(acc[r], z.w, w3);
      }
    }
    const float* bp = (jq < 8) ? bm : bv;
    float4 bb = *(const float4*)(bp + cq);
    const long long sec = (jq < 8) ? (long long)NN*64 : ((long long)NN*64 + (long long)NN*32);
    #pragma unroll
    for (int r=0;r<2;r++){
      float4 v = acc[r];
      v.x += bb.x; v.y += bb.y; v.z += bb.z; v.w += bb.w;
      int rr = rb*2 + r;
      *(float4*)(h3S + rr*64 + ((jq<8)?0:32) + cq) = v;
      int n = base + rr;
      if (n < NN) *(float4*)(out + sec + (long long)n*32 + cq) = v;
    }
  }
  __syncthreads();   // B3
  #pragma unroll
  for (int i=0;i<4;i++){
    int l = tid + 256*i;
    int r = l >> 5, jj = l & 31;
    float mu = h3S[r*64 + jj];
    float lv = h3S[r*64 + 32 + jj];
    unsigned idx = (unsigned)((base + r)*32 + jj);
    float e = eps_at(idx);
    zS[r*ZSSTR + jj] = fmaf(e, expf(0.5f*lv), mu);
  }
  __syncthreads();   // B4
  {
    const int jq = tid & 15, rb = tid >> 4;
    float4 acc[2];
    #pragma unroll
    for (int r=0;r<2;r++) acc[r] = make_float4(0.f,0.f,0.f,0.f);
    for (int k=0;k<32;k+=4){
      float4 w0 = *(const float4*)(Wx + (k+0)*64 + 4*jq);
      float4 w1 = *(const float4*)(Wx + (k+1)*64 + 4*jq);
      float4 w2 = *(const float4*)(Wx + (k+2)*64 + 4*jq);
      float4 w3 = *(const float4*)(Wx + (k+3)*64 + 4*jq);
      #pragma unroll
      for (int r=0;r<2;r++){
        float4 z = *(const float4*)(zS + (rb*2+r)*ZSSTR + k);
        fma4(acc[r], z.x, w0); fma4(acc[r], z.y, w1);
        fma4(acc[r], z.z, w2); fma4(acc[r], z.w, w3);
      }
    }
    float4 bb = *(const float4*)(bx + 4*jq);
    #pragma unroll
    for (int r=0;r<2;r++){
      int n = base + rb*2 + r;
      if (n < NN){
        float4 v = acc[r];
        v.x += bb.x; v.y += bb.y; v.z += bb.z; v.w += bb.w;
        *(float4*)(out + (long long)n*64 + 4*jq) = v;
      }
    }
  }
}

extern "C" void kernel_launch(void* const* d_in, const int* in_sizes, int n_in,
                              void* d_out, int out_size, void* d_ws, size_t ws_size,
                              hipStream_t stream) {
  const float* x     = (const float*)d_in[0];
  const int*   ei    = (const int*)d_in[1];
  const float* ea    = (const float*)d_in[2];
  const float* u     = (const float*)d_in[3];
  const int*   batch = (const int*)d_in[4];
  const float* W1 = (const float*)d_in[6];
  const float* b1 = (const float*)d_in[7];
  const float* g1 = (const float*)d_in[8];
  const float* be1= (const float*)d_in[9];
  const float* W2 = (const float*)d_in[10];
  const float* b2 = (const float*)d_in[11];
  const float* W3 = (const float*)d_in[12];
  const float* b3 = (const float*)d_in[13];
  const float* g3 = (const float*)d_in[14];
  const float* be3= (const float*)d_in[15];
  const float* W4 = (const float*)d_in[16];
  const float* b4 = (const float*)d_in[17];
  const float* g4 = (const float*)d_in[18];
  const float* be4= (const float*)d_in[19];
  const float* Wm = (const float*)d_in[20];
  const float* bm = (const float*)d_in[21];
  const float* Wv = (const float*)d_in[22];
  const float* bv = (const float*)d_in[23];
  const float* Wx = (const float*)d_in[24];
  const float* bx = (const float*)d_in[25];

  char* W = (char*)d_ws;
  size_t off = 0;
  float* h_ws = (float*)(W + off);  off += (size_t)EE*64*4;     // 102.4 MB
  int* cnt      = (int*)(W + off);  off += (size_t)NN*4;
  int* offs     = (int*)(W + off);  off += (size_t)NN*4;
  int* cursor   = (int*)(W + off);  off += (size_t)NN*4;
  int* eidx     = (int*)(W + off);  off += (size_t)EE*4;
  int* partials = (int*)(W + off);  off += 256;
  unsigned short* xb  = (unsigned short*)(W + off); off += (size_t)NN*64*2;  // 6.4 MB
  unsigned short* W1T = (unsigned short*)(W + off); off += 128*128*2;
  unsigned short* W2T = (unsigned short*)(W + off); off += 64*128*2;
  float* out = (float*)d_out;

  hipMemsetAsync(cnt, 0, (size_t)NN*sizeof(int), stream);

  k_prep_x<<<(NN*64/8 + 255)/256, 256, 0, stream>>>(x, xb);
  k_prep_w<<<1, 256, 0, stream>>>(W1, W2, W1T, W2T);
  k_hist <<<(EE+255)/256, 256, 0, stream>>>(ei, cnt);
  k_scan1<<<NB, 256, 0, stream>>>(cnt, offs, partials);
  k_scan2<<<1, 64, 0, stream>>>(partials);
  k_scan3<<<NB, 256, 0, stream>>>(offs, partials, cursor);
  k_fill <<<(EE+255)/256, 256, 0, stream>>>(ei, cursor, eidx);

  k_edge<<<EE/64, 256, 0, stream>>>(ei, ea, xb, W1T, b1, g1, be1, W2T, b2, h_ws);
  k_node<<<(NN+31)/32, 256, 0, stream>>>(x, u, batch, h_ws, cnt, offs, eidx,
                                         W3,b3,g3,be3, W4,b4,g4,be4,
                                         Wm,bm, Wv,bv, Wx,bx, out);
}